// Round 1
// baseline (8769.070 us; speedup 1.0000x reference)
//
#include <hip/hip_runtime.h>
#include <cstdint>
#include <cstddef>

#define DIM_SOL 4096
#define DIM_CTX 4096
#define DIM_HID 8192
#define NWG 32                 // workgroups in the serial phase (one wave each)
#define SLICE (DIM_HID / NWG)  // 256 hidden elems per WG, 4 per lane

// Workspace layout (bytes):
//   [0,     4096)  : pub slots, 2 banks x 32 slots, each slot padded to 64B (u64 used)
//   [4096, 20480)  : pbuf, 4096 floats (per-step p, for logp reduction)
//   [24576,57344)  : a0, 8192 floats
//   [65536, +128MB): Wp packed transpose of W[:,4096:]  (row i = column 4096+i of W)
// Harness poisons ws with 0xAA before every launch: tag 0xAAAAAAAA never equals a
// valid step tag (1..4096), so no slot initialization is needed.

__device__ __forceinline__ float sigmoid_precise(float x) {
    return 1.0f / (1.0f + expf(-x));
}

// ---------------------------------------------------------------------------
// Prep: a0 GEMV (WGs 0..127) + transpose-pack of W's sol half (WGs 128..511)
// ---------------------------------------------------------------------------
__global__ __launch_bounds__(256) void ar_prep(
    const float* __restrict__ W, const float* __restrict__ context,
    const float* __restrict__ c, float* __restrict__ a0,
    float* __restrict__ Wp, int packed)
{
    const int wg  = blockIdx.x;
    const int tid = threadIdx.x;

    if (wg < 128) {
        // a0[r] = c[r] + dot(W[r][0:4096], context); one wave per row-group.
        const int wave = wg * 4 + (tid >> 6);   // 0..511
        const int lane = tid & 63;
        const float4* ctx4 = reinterpret_cast<const float4*>(context);
        const int r0 = wave * 16;               // 512 waves * 16 rows = 8192
        for (int r = r0; r < r0 + 16; ++r) {
            const float4* Wr4 = reinterpret_cast<const float4*>(W + (size_t)r * DIM_HID);
            float acc = 0.f;
#pragma unroll
            for (int j = 0; j < 16; ++j) {
                float4 w4 = Wr4[lane + 64 * j];
                float4 x4 = ctx4[lane + 64 * j];
                acc = fmaf(w4.x, x4.x, acc);
                acc = fmaf(w4.y, x4.y, acc);
                acc = fmaf(w4.z, x4.z, acc);
                acc = fmaf(w4.w, x4.w, acc);
            }
#pragma unroll
            for (int off = 32; off >= 1; off >>= 1) acc += __shfl_xor(acc, off);
            if (lane == 0) a0[r] = c[r] + acc;
        }
    } else if (packed) {
        // Tiled 64x64 transpose: Wp[i][k] = W[k][4096+i]
        __shared__ float tile[64][65];
        const int tx = tid & 63, ty = tid >> 6;   // ty 0..3
        for (int t = wg - 128; t < 64 * 128; t += 384) {
            const int i0 = (t & 63) * 64;   // sol index tile
            const int k0 = (t >> 6) * 64;   // hidden index tile
            __syncthreads();
#pragma unroll
            for (int dy = 0; dy < 64; dy += 4) {
                tile[dy + ty][tx] =
                    W[(size_t)(k0 + dy + ty) * DIM_HID + (DIM_CTX + i0 + tx)];
            }
            __syncthreads();
#pragma unroll
            for (int dy = 0; dy < 64; dy += 4) {
                Wp[(size_t)(i0 + dy + ty) * DIM_HID + (k0 + tx)] = tile[tx][dy + ty];
            }
        }
    }
}

// ---------------------------------------------------------------------------
// Serial autoregressive loop: NWG single-wave workgroups, hidden-dim split.
// ---------------------------------------------------------------------------
__global__ __launch_bounds__(64) void ar_serial(
    const float* __restrict__ V, const float* __restrict__ W,
    const float* __restrict__ b, const float* __restrict__ u,
    const float* __restrict__ a0, const float* __restrict__ Wp,
    unsigned long long* __restrict__ pub,
    float* __restrict__ pbuf, float* __restrict__ out, int packed)
{
    const int g    = blockIdx.x;    // 0..NWG-1
    const int lane = threadIdx.x;   // 0..63
    const int base = g * SLICE + lane * 4;      // 4 consecutive floats per lane
    const int fidx = (base >> 2);               // float4 index within a row

    const float4* V4  = reinterpret_cast<const float4*>(V);
    const float4* Wp4 = reinterpret_cast<const float4*>(Wp);

    float a[4], h[4];
#pragma unroll
    for (int j = 0; j < 4; ++j) {
        a[j] = a0[base + j];
        h[j] = sigmoid_precise(a[j]);
    }

    // Preload step 0 operands.
    float4 Vc = V4[fidx];
    float4 Wc;
    if (packed) {
        Wc = Wp4[fidx];
    } else {
        Wc.x = W[(size_t)(base + 0) * DIM_HID + DIM_CTX + 0];
        Wc.y = W[(size_t)(base + 1) * DIM_HID + DIM_CTX + 0];
        Wc.z = W[(size_t)(base + 2) * DIM_HID + DIM_CTX + 0];
        Wc.w = W[(size_t)(base + 3) * DIM_HID + DIM_CTX + 0];
    }
    float bc = b[0], uc = u[0];

    for (int i = 0; i < DIM_SOL; ++i) {
        // Prefetch next step's operands (independent of this step's result).
        float4 Vn = Vc, Wn = Wc;
        float  bn = bc, un = uc;
        if (i + 1 < DIM_SOL) {
            Vn = V4[(size_t)(i + 1) * (DIM_HID / 4) + fidx];
            if (packed) {
                Wn = Wp4[(size_t)(i + 1) * (DIM_HID / 4) + fidx];
            } else {
                Wn.x = W[(size_t)(base + 0) * DIM_HID + DIM_CTX + (i + 1)];
                Wn.y = W[(size_t)(base + 1) * DIM_HID + DIM_CTX + (i + 1)];
                Wn.z = W[(size_t)(base + 2) * DIM_HID + DIM_CTX + (i + 1)];
                Wn.w = W[(size_t)(base + 3) * DIM_HID + DIM_CTX + (i + 1)];
            }
            bn = b[i + 1];
            un = u[i + 1];
        }

        // Local partial dot of V[i, slice] . h
        float dot = Vc.x * h[0];
        dot = fmaf(Vc.y, h[1], dot);
        dot = fmaf(Vc.z, h[2], dot);
        dot = fmaf(Vc.w, h[3], dot);
#pragma unroll
        for (int off = 32; off >= 1; off >>= 1) dot += __shfl_xor(dot, off);

        // Publish {tag, bits} as one u64 (payload travels with the tag, so
        // relaxed polling is value-correct; release prevents sinking).
        if (lane == 0) {
            unsigned long long val =
                ((unsigned long long)(unsigned)(i + 1) << 32) |
                (unsigned long long)__float_as_uint(dot);
            __hip_atomic_store(pub + (size_t)(i & 1) * 256 + (size_t)g * 8, val,
                               __ATOMIC_RELEASE, __HIP_MEMORY_SCOPE_AGENT);
        }

        // Poll all NWG slots of this step's bank (lane L reads slot L&31).
        unsigned long long vslot;
        {
            unsigned long long* sp =
                pub + (size_t)(i & 1) * 256 + (size_t)(lane & 31) * 8;
            for (;;) {
                vslot = __hip_atomic_load(sp, __ATOMIC_RELAXED,
                                          __HIP_MEMORY_SCOPE_AGENT);
                if (__all((unsigned)(vslot >> 32) == (unsigned)(i + 1))) break;
            }
        }
        float part = __uint_as_float((unsigned)(vslot & 0xffffffffull));
        // Deterministic fixed-order tree over the 32 slot values (offsets <32
        // keep the lower half closed; lane 0 holds the true total).
#pragma unroll
        for (int off = 16; off >= 1; off >>= 1) part += __shfl_xor(part, off);
        const float total = __shfl(part, 0);

        // Every WG computes the identical p, s (bitwise: same ops, same order).
        const float p = sigmoid_precise(bc + total);
        const bool  s = (uc < p);

        if (g == 0 && lane == 0) {
            out[i]  = s ? 1.0f : 0.0f;
            pbuf[i] = p;
        }

        if (s) {
#pragma unroll
            for (int j = 0; j < 4; ++j) {
                a[j] += (j == 0 ? Wc.x : j == 1 ? Wc.y : j == 2 ? Wc.z : Wc.w);
                h[j] = sigmoid_precise(a[j]);
            }
        }

        Vc = Vn; Wc = Wn; bc = bn; uc = un;
    }
}

// ---------------------------------------------------------------------------
// logp = sum_{i<4094} s_i*log(p_i) + (1-s_i)*log1p(-p_i)
// ---------------------------------------------------------------------------
__global__ __launch_bounds__(256) void ar_logp(
    const float* __restrict__ pbuf, float* __restrict__ out)
{
    __shared__ float red[256];
    const int t = threadIdx.x;
    float acc = 0.f;
    for (int i = t; i < DIM_SOL - 2; i += 256) {
        const float p = pbuf[i];
        const float s = out[i];
        acc += (s > 0.5f) ? logf(p) : log1pf(-p);
    }
    red[t] = acc;
    __syncthreads();
    for (int w = 128; w >= 1; w >>= 1) {
        if (t < w) red[t] += red[t + w];
        __syncthreads();
    }
    if (t == 0) out[DIM_SOL] = red[0];
}

// ---------------------------------------------------------------------------
extern "C" void kernel_launch(void* const* d_in, const int* in_sizes, int n_in,
                              void* d_out, int out_size, void* d_ws, size_t ws_size,
                              hipStream_t stream)
{
    const float* context = (const float*)d_in[0];
    const float* u       = (const float*)d_in[1];
    const float* W       = (const float*)d_in[2];
    const float* V       = (const float*)d_in[3];
    const float* b       = (const float*)d_in[4];
    const float* c       = (const float*)d_in[5];
    float* out = (float*)d_out;

    char* ws = (char*)d_ws;
    unsigned long long* pub = (unsigned long long*)(ws);
    float* pbuf = (float*)(ws + 4096);
    float* a0   = (float*)(ws + 24576);
    float* Wp   = (float*)(ws + 65536);
    const size_t wp_bytes = (size_t)DIM_SOL * DIM_HID * sizeof(float);
    const int packed = (ws_size >= (size_t)65536 + wp_bytes) ? 1 : 0;

    hipLaunchKernelGGL(ar_prep, dim3(512), dim3(256), 0, stream,
                       W, context, c, a0, Wp, packed);
    hipLaunchKernelGGL(ar_serial, dim3(NWG), dim3(64), 0, stream,
                       V, W, b, u, a0, Wp, pub, pbuf, out, packed);
    hipLaunchKernelGGL(ar_logp, dim3(1), dim3(256), 0, stream, pbuf, out);
}

// Round 2
// 6782.632 us; speedup vs baseline: 1.2929x; 1.2929x over previous
//
#include <hip/hip_runtime.h>
#include <cstdint>
#include <cstddef>

#define DIM_SOL 4096
#define DIM_CTX 4096
#define DIM_HID 8192
#define NWG 32                 // serial-phase workgroups (one wave each)
#define SLICE (DIM_HID / NWG)  // 256 hidden elems per WG, 4 per lane
#define NROUND (DIM_SOL / 4)   // K=4 steps per sync round

// Workspace layout (bytes):
//   [0,     4096)  : pub slots, 2 banks x 32 slots x 64B (8 u64: {tag,d0},{d1,d2}..{d13,d14})
//   [4096, 20480)  : pbuf, 4096 floats (per-step p, for logp reduction)
//   [24576,57344)  : a0, 8192 floats
//   [65536, +128MB): Wp packed transpose of W[:,4096:] (row i = column 4096+i of W)
// Harness re-poisons ws with 0xAA before every launch: tag dword 0xAAAAAAAA never
// equals a valid round tag (1..1024), so slots need no initialization.

__device__ __forceinline__ float sigmoid_precise(float x) {
    return 1.0f / (1.0f + expf(-x));
}
__device__ __forceinline__ float dot4(float4 v, float4 h) {
    float d = v.x * h.x;
    d = fmaf(v.y, h.y, d);
    d = fmaf(v.z, h.z, d);
    d = fmaf(v.w, h.w, d);
    return d;
}
__device__ __forceinline__ float4 sig4(float4 x) {
    float4 r;
    r.x = sigmoid_precise(x.x); r.y = sigmoid_precise(x.y);
    r.z = sigmoid_precise(x.z); r.w = sigmoid_precise(x.w);
    return r;
}
__device__ __forceinline__ float4 add4(float4 a, float4 w) {
    float4 r; r.x = a.x + w.x; r.y = a.y + w.y; r.z = a.z + w.z; r.w = a.w + w.w;
    return r;
}
__device__ __forceinline__ unsigned long long packf2(float lo, float hi) {
    return ((unsigned long long)__float_as_uint(hi) << 32) |
           (unsigned long long)__float_as_uint(lo);
}

// ---------------------------------------------------------------------------
// Prep: a0 GEMV (WGs 0..127) + transpose-pack of W's sol half (WGs 128..1023)
// ---------------------------------------------------------------------------
__global__ __launch_bounds__(256) void ar_prep(
    const float* __restrict__ W, const float* __restrict__ context,
    const float* __restrict__ c, float* __restrict__ a0,
    float* __restrict__ Wp, int packed)
{
    const int wg  = blockIdx.x;
    const int tid = threadIdx.x;

    if (wg < 128) {
        // a0[r] = c[r] + dot(W[r][0:4096], context); one wave per 16-row group.
        const int wave = wg * 4 + (tid >> 6);   // 0..511
        const int lane = tid & 63;
        const float4* ctx4 = reinterpret_cast<const float4*>(context);
        const int r0 = wave * 16;
        for (int r = r0; r < r0 + 16; ++r) {
            const float4* Wr4 = reinterpret_cast<const float4*>(W + (size_t)r * DIM_HID);
            float acc = 0.f;
#pragma unroll
            for (int j = 0; j < 16; ++j) {
                float4 w4 = Wr4[lane + 64 * j];
                float4 x4 = ctx4[lane + 64 * j];
                acc = fmaf(w4.x, x4.x, acc);
                acc = fmaf(w4.y, x4.y, acc);
                acc = fmaf(w4.z, x4.z, acc);
                acc = fmaf(w4.w, x4.w, acc);
            }
#pragma unroll
            for (int off = 32; off >= 1; off >>= 1) acc += __shfl_xor(acc, off);
            if (lane == 0) a0[r] = c[r] + acc;
        }
    } else if (packed) {
        // Tiled 64x64 transpose: Wp[i][k] = W[k][4096+i]
        __shared__ float tile[64][65];
        const int tx = tid & 63, ty = tid >> 6;   // ty 0..3
        for (int t = wg - 128; t < 64 * 128; t += 896) {
            const int i0 = (t & 63) * 64;   // sol tile
            const int k0 = (t >> 6) * 64;   // hidden tile
            __syncthreads();
#pragma unroll
            for (int dy = 0; dy < 64; dy += 4) {
                tile[dy + ty][tx] =
                    W[(size_t)(k0 + dy + ty) * DIM_HID + (DIM_CTX + i0 + tx)];
            }
            __syncthreads();
#pragma unroll
            for (int dy = 0; dy < 64; dy += 4) {
                Wp[(size_t)(i0 + dy + ty) * DIM_HID + (k0 + tx)] = tile[tx][dy + ty];
            }
        }
    }
}

// ---------------------------------------------------------------------------
// Serial phase: K=4 speculative steps per global sync round.
// 15 tree nodes, heap order: node(d,b) = 2^d-1+b, b = sum s_{i+k} 2^k.
// ---------------------------------------------------------------------------
__global__ __launch_bounds__(64) void ar_serial(
    const float* __restrict__ V, const float* __restrict__ W,
    const float* __restrict__ b, const float* __restrict__ u,
    const float* __restrict__ a0, const float* __restrict__ Wp,
    unsigned long long* __restrict__ pub,
    float* __restrict__ pbuf, float* __restrict__ out, int packed)
{
    const int g    = blockIdx.x;
    const int lane = threadIdx.x;
    const int base = g * SLICE + lane * 4;
    const int fidx = base >> 2;                  // float4 index within a row

    const float4* V4  = reinterpret_cast<const float4*>(V);
    const float4* Wp4 = reinterpret_cast<const float4*>(Wp);
    const float4* b4  = reinterpret_cast<const float4*>(b);
    const float4* u4  = reinterpret_cast<const float4*>(u);

    float4 a4 = *reinterpret_cast<const float4*>(a0 + base);

    // Row loader for W's sol column i (packed or strided fallback).
    auto loadW = [&](int i) -> float4 {
        if (packed) return Wp4[(size_t)i * (DIM_HID / 4) + fidx];
        float4 w;
        w.x = W[(size_t)(base + 0) * DIM_HID + DIM_CTX + i];
        w.y = W[(size_t)(base + 1) * DIM_HID + DIM_CTX + i];
        w.z = W[(size_t)(base + 2) * DIM_HID + DIM_CTX + i];
        w.w = W[(size_t)(base + 3) * DIM_HID + DIM_CTX + i];
        return w;
    };

    // Preload round 0 operands.
    float4 Vr0 = V4[(size_t)0 * 2048 + fidx], Vr1 = V4[(size_t)1 * 2048 + fidx];
    float4 Vr2 = V4[(size_t)2 * 2048 + fidx], Vr3 = V4[(size_t)3 * 2048 + fidx];
    float4 Wr0 = loadW(0), Wr1 = loadW(1), Wr2 = loadW(2), Wr3 = loadW(3);
    float4 bb = b4[0], uu = u4[0];

    for (int r = 0; r < NROUND; ++r) {
        const unsigned tag = (unsigned)(r + 1);
        unsigned long long* bank = pub + (size_t)(r & 1) * 256;

        // ---- 15 speculative dots over the 8 subsets of {Wr0,Wr1,Wr2}.
        // Additions are ascending-k from a4, matching the reference's
        // sequential update order bit-exactly on the realized path.
        float d0,d1,d2,d3,d4,d5,d6,d7,d8,d9,d10,d11,d12,d13,d14;
        {
            float4 hs;
            hs = sig4(a4);                                   // m=0: {}
            d0 = dot4(Vr0, hs); d1 = dot4(Vr1, hs); d3 = dot4(Vr2, hs); d7 = dot4(Vr3, hs);
            hs = sig4(add4(a4, Wr0));                        // m=1: {0}
            d2 = dot4(Vr1, hs); d4 = dot4(Vr2, hs); d8 = dot4(Vr3, hs);
            hs = sig4(add4(a4, Wr1));                        // m=2: {1}
            d5 = dot4(Vr2, hs); d9 = dot4(Vr3, hs);
            hs = sig4(add4(add4(a4, Wr0), Wr1));             // m=3: {0,1}
            d6 = dot4(Vr2, hs); d10 = dot4(Vr3, hs);
            hs = sig4(add4(a4, Wr2));                        // m=4: {2}
            d11 = dot4(Vr3, hs);
            hs = sig4(add4(add4(a4, Wr0), Wr2));             // m=5: {0,2}
            d12 = dot4(Vr3, hs);
            hs = sig4(add4(add4(a4, Wr1), Wr2));             // m=6: {1,2}
            d13 = dot4(Vr3, hs);
            hs = sig4(add4(add4(add4(a4, Wr0), Wr1), Wr2));  // m=7: {0,1,2}
            d14 = dot4(Vr3, hs);
        }

        // ---- In-wave butterfly reduce all 15 dots (all lanes end with sums).
#define RED_ALL(OFF) \
        d0 += __shfl_xor(d0, OFF);  d1 += __shfl_xor(d1, OFF);  d2 += __shfl_xor(d2, OFF); \
        d3 += __shfl_xor(d3, OFF);  d4 += __shfl_xor(d4, OFF);  d5 += __shfl_xor(d5, OFF); \
        d6 += __shfl_xor(d6, OFF);  d7 += __shfl_xor(d7, OFF);  d8 += __shfl_xor(d8, OFF); \
        d9 += __shfl_xor(d9, OFF);  d10 += __shfl_xor(d10, OFF); d11 += __shfl_xor(d11, OFF); \
        d12 += __shfl_xor(d12, OFF); d13 += __shfl_xor(d13, OFF); d14 += __shfl_xor(d14, OFF);
        RED_ALL(1) RED_ALL(2) RED_ALL(4) RED_ALL(8) RED_ALL(16) RED_ALL(32)
#undef RED_ALL

        // ---- Publish: payload u64s relaxed, then fence, then tagged u64.
        {
            unsigned long long* slot = bank + (size_t)g * 8;
            if (lane >= 1 && lane < 8) {
                float lo = (lane == 1) ? d1 : (lane == 2) ? d3 : (lane == 3) ? d5 :
                           (lane == 4) ? d7 : (lane == 5) ? d9 : (lane == 6) ? d11 : d13;
                float hi = (lane == 1) ? d2 : (lane == 2) ? d4 : (lane == 3) ? d6 :
                           (lane == 4) ? d8 : (lane == 5) ? d10 : (lane == 6) ? d12 : d14;
                __hip_atomic_store(slot + lane, packf2(lo, hi),
                                   __ATOMIC_RELAXED, __HIP_MEMORY_SCOPE_AGENT);
            }
            __threadfence();
            if (lane == 0) {
                unsigned long long v =
                    ((unsigned long long)__float_as_uint(d0) << 32) |
                    (unsigned long long)tag;
                __hip_atomic_store(slot, v, __ATOMIC_RELEASE, __HIP_MEMORY_SCOPE_AGENT);
            }
        }

        // ---- Prefetch next round's rows while the sync is in flight.
        float4 Vn0, Vn1, Vn2, Vn3, Wn0, Wn1, Wn2, Wn3, bbn, uun;
        if (r + 1 < NROUND) {
            const int i1 = 4 * (r + 1);
            Vn0 = V4[(size_t)(i1 + 0) * 2048 + fidx];
            Vn1 = V4[(size_t)(i1 + 1) * 2048 + fidx];
            Vn2 = V4[(size_t)(i1 + 2) * 2048 + fidx];
            Vn3 = V4[(size_t)(i1 + 3) * 2048 + fidx];
            Wn0 = loadW(i1 + 0); Wn1 = loadW(i1 + 1);
            Wn2 = loadW(i1 + 2); Wn3 = loadW(i1 + 3);
            bbn = b4[r + 1]; uun = u4[r + 1];
        }

        // ---- Poll: lane pair 2s,2s+1 owns slot s; per-lane divergent spin.
        unsigned long long* myslot = bank + (size_t)(lane >> 1) * 8;
        unsigned long long q0;
        do {
            q0 = __hip_atomic_load(myslot, __ATOMIC_ACQUIRE, __HIP_MEMORY_SCOPE_AGENT);
        } while ((unsigned)(q0 & 0xffffffffull) != tag);

        float v0, v1, v2, v3, v4, v5, v6, v7;
        if (lane & 1) {
            unsigned long long q4 = __hip_atomic_load(myslot + 4, __ATOMIC_RELAXED, __HIP_MEMORY_SCOPE_AGENT);
            unsigned long long q5 = __hip_atomic_load(myslot + 5, __ATOMIC_RELAXED, __HIP_MEMORY_SCOPE_AGENT);
            unsigned long long q6 = __hip_atomic_load(myslot + 6, __ATOMIC_RELAXED, __HIP_MEMORY_SCOPE_AGENT);
            unsigned long long q7 = __hip_atomic_load(myslot + 7, __ATOMIC_RELAXED, __HIP_MEMORY_SCOPE_AGENT);
            v0 = __uint_as_float((unsigned)(q4 & 0xffffffffull));   // d7
            v1 = __uint_as_float((unsigned)(q4 >> 32));             // d8
            v2 = __uint_as_float((unsigned)(q5 & 0xffffffffull));   // d9
            v3 = __uint_as_float((unsigned)(q5 >> 32));             // d10
            v4 = __uint_as_float((unsigned)(q6 & 0xffffffffull));   // d11
            v5 = __uint_as_float((unsigned)(q6 >> 32));             // d12
            v6 = __uint_as_float((unsigned)(q7 & 0xffffffffull));   // d13
            v7 = __uint_as_float((unsigned)(q7 >> 32));             // d14
        } else {
            unsigned long long q1 = __hip_atomic_load(myslot + 1, __ATOMIC_RELAXED, __HIP_MEMORY_SCOPE_AGENT);
            unsigned long long q2 = __hip_atomic_load(myslot + 2, __ATOMIC_RELAXED, __HIP_MEMORY_SCOPE_AGENT);
            unsigned long long q3 = __hip_atomic_load(myslot + 3, __ATOMIC_RELAXED, __HIP_MEMORY_SCOPE_AGENT);
            v0 = __uint_as_float((unsigned)(q0 >> 32));             // d0
            v1 = __uint_as_float((unsigned)(q1 & 0xffffffffull));   // d1
            v2 = __uint_as_float((unsigned)(q1 >> 32));             // d2
            v3 = __uint_as_float((unsigned)(q2 & 0xffffffffull));   // d3
            v4 = __uint_as_float((unsigned)(q2 >> 32));             // d4
            v5 = __uint_as_float((unsigned)(q3 & 0xffffffffull));   // d5
            v6 = __uint_as_float((unsigned)(q3 >> 32));             // d6
            v7 = 0.0f;
        }

        // ---- Reduce across the 32 slots (butterfly over lane-pairs).
#define REDS(OFF) \
        v0 += __shfl_xor(v0, OFF); v1 += __shfl_xor(v1, OFF); v2 += __shfl_xor(v2, OFF); \
        v3 += __shfl_xor(v3, OFF); v4 += __shfl_xor(v4, OFF); v5 += __shfl_xor(v5, OFF); \
        v6 += __shfl_xor(v6, OFF); v7 += __shfl_xor(v7, OFF);
        REDS(2) REDS(4) REDS(8) REDS(16) REDS(32)
#undef REDS

        // Broadcast node totals to all lanes (uniform values).
        const float T0 = __shfl(v0, 0), T1 = __shfl(v1, 0), T2 = __shfl(v2, 0);
        const float T3 = __shfl(v3, 0), T4 = __shfl(v4, 0), T5 = __shfl(v5, 0);
        const float T6 = __shfl(v6, 0);
        const float T7 = __shfl(v0, 1), T8 = __shfl(v1, 1), T9 = __shfl(v2, 1);
        const float T10 = __shfl(v3, 1), T11 = __shfl(v4, 1), T12 = __shfl(v5, 1);
        const float T13 = __shfl(v6, 1), T14 = __shfl(v7, 1);

        // ---- Decode 4 steps (identical uniform computation in every WG).
        const float p0 = sigmoid_precise(bb.x + T0);
        const bool  s0 = uu.x < p0;
        const float p1 = sigmoid_precise(bb.y + (s0 ? T2 : T1));
        const bool  s1 = uu.y < p1;
        const float t2a = s0 ? T4 : T3, t2b = s0 ? T6 : T5;
        const float p2 = sigmoid_precise(bb.z + (s1 ? t2b : t2a));
        const bool  s2 = uu.z < p2;
        const float t3a = s0 ? T8 : T7,  t3b = s0 ? T10 : T9;
        const float t3c = s0 ? T12 : T11, t3d = s0 ? T14 : T13;
        const float t3e = s1 ? t3b : t3a, t3f = s1 ? t3d : t3c;
        const float p3 = sigmoid_precise(bb.w + (s2 ? t3f : t3e));
        const bool  s3 = uu.w < p3;

        if (g == 0 && lane == 0) {
            const int i = 4 * r;
            float4 so; so.x = s0 ? 1.f : 0.f; so.y = s1 ? 1.f : 0.f;
            so.z = s2 ? 1.f : 0.f; so.w = s3 ? 1.f : 0.f;
            *reinterpret_cast<float4*>(out + i) = so;
            float4 po; po.x = p0; po.y = p1; po.z = p2; po.w = p3;
            *reinterpret_cast<float4*>(pbuf + i) = po;
        }

        // ---- Commit a (ascending step order; adding 0 is exact).
        if (s0) a4 = add4(a4, Wr0);
        if (s1) a4 = add4(a4, Wr1);
        if (s2) a4 = add4(a4, Wr2);
        if (s3) a4 = add4(a4, Wr3);

        Vr0 = Vn0; Vr1 = Vn1; Vr2 = Vn2; Vr3 = Vn3;
        Wr0 = Wn0; Wr1 = Wn1; Wr2 = Wn2; Wr3 = Wn3;
        bb = bbn; uu = uun;
    }
}

// ---------------------------------------------------------------------------
// logp = sum_{i<4094} s_i*log(p_i) + (1-s_i)*log1p(-p_i)
// ---------------------------------------------------------------------------
__global__ __launch_bounds__(256) void ar_logp(
    const float* __restrict__ pbuf, float* __restrict__ out)
{
    __shared__ float red[256];
    const int t = threadIdx.x;
    float acc = 0.f;
    for (int i = t; i < DIM_SOL - 2; i += 256) {
        const float p = pbuf[i];
        const float s = out[i];
        acc += (s > 0.5f) ? logf(p) : log1pf(-p);
    }
    red[t] = acc;
    __syncthreads();
    for (int w = 128; w >= 1; w >>= 1) {
        if (t < w) red[t] += red[t + w];
        __syncthreads();
    }
    if (t == 0) out[DIM_SOL] = red[0];
}

// ---------------------------------------------------------------------------
extern "C" void kernel_launch(void* const* d_in, const int* in_sizes, int n_in,
                              void* d_out, int out_size, void* d_ws, size_t ws_size,
                              hipStream_t stream)
{
    const float* context = (const float*)d_in[0];
    const float* u       = (const float*)d_in[1];
    const float* W       = (const float*)d_in[2];
    const float* V       = (const float*)d_in[3];
    const float* b       = (const float*)d_in[4];
    const float* c       = (const float*)d_in[5];
    float* out = (float*)d_out;

    char* ws = (char*)d_ws;
    unsigned long long* pub = (unsigned long long*)(ws);
    float* pbuf = (float*)(ws + 4096);
    float* a0   = (float*)(ws + 24576);
    float* Wp   = (float*)(ws + 65536);
    const size_t wp_bytes = (size_t)DIM_SOL * DIM_HID * sizeof(float);
    const int packed = (ws_size >= (size_t)65536 + wp_bytes) ? 1 : 0;

    hipLaunchKernelGGL(ar_prep, dim3(1024), dim3(256), 0, stream,
                       W, context, c, a0, Wp, packed);
    hipLaunchKernelGGL(ar_serial, dim3(NWG), dim3(64), 0, stream,
                       V, W, b, u, a0, Wp, pub, pbuf, out, packed);
    hipLaunchKernelGGL(ar_logp, dim3(1), dim3(256), 0, stream, pbuf, out);
}

// Round 3
// 5144.228 us; speedup vs baseline: 1.7046x; 1.3185x over previous
//
#include <hip/hip_runtime.h>
#include <cstdint>
#include <cstddef>

#define DIM_SOL 4096
#define DIM_CTX 4096
#define DIM_HID 8192
#define NWG 32                 // serial-phase workgroups (one wave each)
#define SLICE (DIM_HID / NWG)  // 256 hidden elems per WG, 4 per lane
#define NROUND (DIM_SOL / 4)   // K=4 steps per sync round

// Workspace layout (bytes):
//   [0,     8192)  : pub slots, 2 banks x 32 slots x 128B (16 u64; word w = {tag32|d_w bits})
//   [8192, 24576)  : pbuf, 4096 floats (per-step p, for logp reduction)
//   [24576,57344)  : a0, 8192 floats
//   [65536, +128MB): Wp packed transpose of W[:,4096:] (row i = column 4096+i of W)
// All pub traffic is RELAXED agent-scope atomics: each u64 carries its own tag,
// so no fences / acquire / release are needed -> no buffer_wbl2 / buffer_inv
// (those cache-maintenance ops were the round-2 bottleneck).
// Harness re-poisons ws with 0xAA: tag dword 0xAAAAAAAA never equals a valid
// round tag (1..1024), so slots need no initialization.

__device__ __forceinline__ float sigmoid_precise(float x) {
    return 1.0f / (1.0f + expf(-x));
}
__device__ __forceinline__ float dot4(float4 v, float4 h) {
    float d = v.x * h.x;
    d = fmaf(v.y, h.y, d);
    d = fmaf(v.z, h.z, d);
    d = fmaf(v.w, h.w, d);
    return d;
}
__device__ __forceinline__ float4 sig4(float4 x) {
    float4 r;
    r.x = sigmoid_precise(x.x); r.y = sigmoid_precise(x.y);
    r.z = sigmoid_precise(x.z); r.w = sigmoid_precise(x.w);
    return r;
}
__device__ __forceinline__ float4 add4(float4 a, float4 w) {
    float4 r; r.x = a.x + w.x; r.y = a.y + w.y; r.z = a.z + w.z; r.w = a.w + w.w;
    return r;
}

// ---------------------------------------------------------------------------
// Prep: a0 GEMV (WGs 0..127) + transpose-pack of W's sol half (WGs 128..1023)
// ---------------------------------------------------------------------------
__global__ __launch_bounds__(256) void ar_prep(
    const float* __restrict__ W, const float* __restrict__ context,
    const float* __restrict__ c, float* __restrict__ a0,
    float* __restrict__ Wp, int packed)
{
    const int wg  = blockIdx.x;
    const int tid = threadIdx.x;

    if (wg < 128) {
        // a0[r] = c[r] + dot(W[r][0:4096], context); one wave per 16-row group.
        const int wave = wg * 4 + (tid >> 6);   // 0..511
        const int lane = tid & 63;
        const float4* ctx4 = reinterpret_cast<const float4*>(context);
        const int r0 = wave * 16;
        for (int r = r0; r < r0 + 16; ++r) {
            const float4* Wr4 = reinterpret_cast<const float4*>(W + (size_t)r * DIM_HID);
            float acc = 0.f;
#pragma unroll
            for (int j = 0; j < 16; ++j) {
                float4 w4 = Wr4[lane + 64 * j];
                float4 x4 = ctx4[lane + 64 * j];
                acc = fmaf(w4.x, x4.x, acc);
                acc = fmaf(w4.y, x4.y, acc);
                acc = fmaf(w4.z, x4.z, acc);
                acc = fmaf(w4.w, x4.w, acc);
            }
#pragma unroll
            for (int off = 32; off >= 1; off >>= 1) acc += __shfl_xor(acc, off);
            if (lane == 0) a0[r] = c[r] + acc;
        }
    } else if (packed) {
        // Tiled 64x64 transpose: Wp[i][k] = W[k][4096+i]
        __shared__ float tile[64][65];
        const int tx = tid & 63, ty = tid >> 6;   // ty 0..3
        for (int t = wg - 128; t < 64 * 128; t += 896) {
            const int i0 = (t & 63) * 64;   // sol tile
            const int k0 = (t >> 6) * 64;   // hidden tile
            __syncthreads();
#pragma unroll
            for (int dy = 0; dy < 64; dy += 4) {
                tile[dy + ty][tx] =
                    W[(size_t)(k0 + dy + ty) * DIM_HID + (DIM_CTX + i0 + tx)];
            }
            __syncthreads();
#pragma unroll
            for (int dy = 0; dy < 64; dy += 4) {
                Wp[(size_t)(i0 + dy + ty) * DIM_HID + (k0 + tx)] = tile[tx][dy + ty];
            }
        }
    }
}

// ---------------------------------------------------------------------------
// Serial phase: K=4 speculative steps per all-relaxed global sync round.
// 15 tree nodes, heap order: node(d,b) = 2^d-1+b, b = sum s_{i+k} 2^k.
// ---------------------------------------------------------------------------
__global__ __launch_bounds__(64) void ar_serial(
    const float* __restrict__ V, const float* __restrict__ W,
    const float* __restrict__ b, const float* __restrict__ u,
    const float* __restrict__ a0, const float* __restrict__ Wp,
    unsigned long long* __restrict__ pub,
    float* __restrict__ pbuf, float* __restrict__ out, int packed)
{
    const int g    = blockIdx.x;
    const int lane = threadIdx.x;
    const int base = g * SLICE + lane * 4;
    const int fidx = base >> 2;                  // float4 index within a row

    const float4* V4  = reinterpret_cast<const float4*>(V);
    const float4* Wp4 = reinterpret_cast<const float4*>(Wp);
    const float4* b4  = reinterpret_cast<const float4*>(b);
    const float4* u4  = reinterpret_cast<const float4*>(u);

    float4 a4 = *reinterpret_cast<const float4*>(a0 + base);

    auto loadW = [&](int i) -> float4 {
        if (packed) return Wp4[(size_t)i * (DIM_HID / 4) + fidx];
        float4 w;
        w.x = W[(size_t)(base + 0) * DIM_HID + DIM_CTX + i];
        w.y = W[(size_t)(base + 1) * DIM_HID + DIM_CTX + i];
        w.z = W[(size_t)(base + 2) * DIM_HID + DIM_CTX + i];
        w.w = W[(size_t)(base + 3) * DIM_HID + DIM_CTX + i];
        return w;
    };

    float4 Vr0 = V4[(size_t)0 * 2048 + fidx], Vr1 = V4[(size_t)1 * 2048 + fidx];
    float4 Vr2 = V4[(size_t)2 * 2048 + fidx], Vr3 = V4[(size_t)3 * 2048 + fidx];
    float4 Wr0 = loadW(0), Wr1 = loadW(1), Wr2 = loadW(2), Wr3 = loadW(3);
    float4 bb = b4[0], uu = u4[0];

    for (int r = 0; r < NROUND; ++r) {
        const unsigned tag = (unsigned)(r + 1);
        unsigned long long* bank = pub + (size_t)(r & 1) * 512;   // 32 slots * 16 u64

        // ---- 15 speculative dots over the 8 subsets of {Wr0,Wr1,Wr2}.
        float d0,d1,d2,d3,d4,d5,d6,d7,d8,d9,d10,d11,d12,d13,d14;
        {
            float4 hs;
            hs = sig4(a4);                                   // m=0: {}
            d0 = dot4(Vr0, hs); d1 = dot4(Vr1, hs); d3 = dot4(Vr2, hs); d7 = dot4(Vr3, hs);
            hs = sig4(add4(a4, Wr0));                        // m=1: {0}
            d2 = dot4(Vr1, hs); d4 = dot4(Vr2, hs); d8 = dot4(Vr3, hs);
            hs = sig4(add4(a4, Wr1));                        // m=2: {1}
            d5 = dot4(Vr2, hs); d9 = dot4(Vr3, hs);
            hs = sig4(add4(add4(a4, Wr0), Wr1));             // m=3: {0,1}
            d6 = dot4(Vr2, hs); d10 = dot4(Vr3, hs);
            hs = sig4(add4(a4, Wr2));                        // m=4: {2}
            d11 = dot4(Vr3, hs);
            hs = sig4(add4(add4(a4, Wr0), Wr2));             // m=5: {0,2}
            d12 = dot4(Vr3, hs);
            hs = sig4(add4(add4(a4, Wr1), Wr2));             // m=6: {1,2}
            d13 = dot4(Vr3, hs);
            hs = sig4(add4(add4(add4(a4, Wr0), Wr1), Wr2));  // m=7: {0,1,2}
            d14 = dot4(Vr3, hs);
        }

        // ---- In-wave butterfly reduce all 15 dots (all lanes end with sums).
#define RED_ALL(OFF) \
        d0 += __shfl_xor(d0, OFF);  d1 += __shfl_xor(d1, OFF);  d2 += __shfl_xor(d2, OFF); \
        d3 += __shfl_xor(d3, OFF);  d4 += __shfl_xor(d4, OFF);  d5 += __shfl_xor(d5, OFF); \
        d6 += __shfl_xor(d6, OFF);  d7 += __shfl_xor(d7, OFF);  d8 += __shfl_xor(d8, OFF); \
        d9 += __shfl_xor(d9, OFF);  d10 += __shfl_xor(d10, OFF); d11 += __shfl_xor(d11, OFF); \
        d12 += __shfl_xor(d12, OFF); d13 += __shfl_xor(d13, OFF); d14 += __shfl_xor(d14, OFF);
        RED_ALL(1) RED_ALL(2) RED_ALL(4) RED_ALL(8) RED_ALL(16) RED_ALL(32)
#undef RED_ALL

        // ---- Publish: lane w (w<15) stores word w = {d_w bits | tag}, RELAXED.
        {
            float dv =
                (lane == 0) ? d0 : (lane == 1) ? d1 : (lane == 2) ? d2 :
                (lane == 3) ? d3 : (lane == 4) ? d4 : (lane == 5) ? d5 :
                (lane == 6) ? d6 : (lane == 7) ? d7 : (lane == 8) ? d8 :
                (lane == 9) ? d9 : (lane == 10) ? d10 : (lane == 11) ? d11 :
                (lane == 12) ? d12 : (lane == 13) ? d13 : d14;
            if (lane < 15) {
                unsigned long long v =
                    ((unsigned long long)__float_as_uint(dv) << 32) |
                    (unsigned long long)tag;
                __hip_atomic_store(bank + (size_t)g * 16 + lane, v,
                                   __ATOMIC_RELAXED, __HIP_MEMORY_SCOPE_AGENT);
            }
        }

        // ---- Prefetch next round's rows while the sync is in flight.
        float4 Vn0, Vn1, Vn2, Vn3, Wn0, Wn1, Wn2, Wn3, bbn, uun;
        if (r + 1 < NROUND) {
            const int i1 = 4 * (r + 1);
            Vn0 = V4[(size_t)(i1 + 0) * 2048 + fidx];
            Vn1 = V4[(size_t)(i1 + 1) * 2048 + fidx];
            Vn2 = V4[(size_t)(i1 + 2) * 2048 + fidx];
            Vn3 = V4[(size_t)(i1 + 3) * 2048 + fidx];
            Wn0 = loadW(i1 + 0); Wn1 = loadW(i1 + 1);
            Wn2 = loadW(i1 + 2); Wn3 = loadW(i1 + 3);
            bbn = b4[r + 1]; uun = u4[r + 1];
        }

        // ---- Poll: even lane owns words 0..7 of slot (lane>>1), odd words 8..14.
        unsigned long long q0,q1,q2,q3,q4,q5,q6,q7;
        {
            unsigned long long* ms =
                bank + (size_t)(lane >> 1) * 16 + ((lane & 1) ? 8 : 0);
            const bool odd = (lane & 1);
            for (;;) {
                q0 = __hip_atomic_load(ms + 0, __ATOMIC_RELAXED, __HIP_MEMORY_SCOPE_AGENT);
                q1 = __hip_atomic_load(ms + 1, __ATOMIC_RELAXED, __HIP_MEMORY_SCOPE_AGENT);
                q2 = __hip_atomic_load(ms + 2, __ATOMIC_RELAXED, __HIP_MEMORY_SCOPE_AGENT);
                q3 = __hip_atomic_load(ms + 3, __ATOMIC_RELAXED, __HIP_MEMORY_SCOPE_AGENT);
                q4 = __hip_atomic_load(ms + 4, __ATOMIC_RELAXED, __HIP_MEMORY_SCOPE_AGENT);
                q5 = __hip_atomic_load(ms + 5, __ATOMIC_RELAXED, __HIP_MEMORY_SCOPE_AGENT);
                q6 = __hip_atomic_load(ms + 6, __ATOMIC_RELAXED, __HIP_MEMORY_SCOPE_AGENT);
                q7 = odd ? ((unsigned long long)tag)
                         : __hip_atomic_load(ms + 7, __ATOMIC_RELAXED, __HIP_MEMORY_SCOPE_AGENT);
                bool ok = ((unsigned)q0 == tag) & ((unsigned)q1 == tag) &
                          ((unsigned)q2 == tag) & ((unsigned)q3 == tag) &
                          ((unsigned)q4 == tag) & ((unsigned)q5 == tag) &
                          ((unsigned)q6 == tag) & ((unsigned)q7 == tag);
                if (__all(ok)) break;
            }
        }
        // Payload floats: even lane -> d0..d7 of its slot; odd lane -> d8..d14.
        float v0 = __uint_as_float((unsigned)(q0 >> 32));
        float v1 = __uint_as_float((unsigned)(q1 >> 32));
        float v2 = __uint_as_float((unsigned)(q2 >> 32));
        float v3 = __uint_as_float((unsigned)(q3 >> 32));
        float v4 = __uint_as_float((unsigned)(q4 >> 32));
        float v5 = __uint_as_float((unsigned)(q5 >> 32));
        float v6 = __uint_as_float((unsigned)(q6 >> 32));
        float v7 = (lane & 1) ? 0.0f : __uint_as_float((unsigned)(q7 >> 32));

        // ---- Reduce across the 32 slots (even offsets keep lane parity).
#define REDS(OFF) \
        v0 += __shfl_xor(v0, OFF); v1 += __shfl_xor(v1, OFF); v2 += __shfl_xor(v2, OFF); \
        v3 += __shfl_xor(v3, OFF); v4 += __shfl_xor(v4, OFF); v5 += __shfl_xor(v5, OFF); \
        v6 += __shfl_xor(v6, OFF); v7 += __shfl_xor(v7, OFF);
        REDS(2) REDS(4) REDS(8) REDS(16) REDS(32)
#undef REDS

        // Broadcast node totals (lane 0: d0..d7 sums; lane 1: d8..d14 sums).
        const float T0 = __shfl(v0, 0), T1 = __shfl(v1, 0), T2 = __shfl(v2, 0);
        const float T3 = __shfl(v3, 0), T4 = __shfl(v4, 0), T5 = __shfl(v5, 0);
        const float T6 = __shfl(v6, 0), T7 = __shfl(v7, 0);
        const float T8 = __shfl(v0, 1), T9 = __shfl(v1, 1), T10 = __shfl(v2, 1);
        const float T11 = __shfl(v3, 1), T12 = __shfl(v4, 1), T13 = __shfl(v5, 1);
        const float T14 = __shfl(v6, 1);

        // ---- Decode 4 steps (identical uniform computation in every WG).
        const float p0 = sigmoid_precise(bb.x + T0);
        const bool  s0 = uu.x < p0;
        const float p1 = sigmoid_precise(bb.y + (s0 ? T2 : T1));
        const bool  s1 = uu.y < p1;
        const float t2a = s0 ? T4 : T3, t2b = s0 ? T6 : T5;
        const float p2 = sigmoid_precise(bb.z + (s1 ? t2b : t2a));
        const bool  s2 = uu.z < p2;
        const float t3a = s0 ? T8 : T7,  t3b = s0 ? T10 : T9;
        const float t3c = s0 ? T12 : T11, t3d = s0 ? T14 : T13;
        const float t3e = s1 ? t3b : t3a, t3f = s1 ? t3d : t3c;
        const float p3 = sigmoid_precise(bb.w + (s2 ? t3f : t3e));
        const bool  s3 = uu.w < p3;

        if (g == 0 && lane == 0) {
            const int i = 4 * r;
            float4 so; so.x = s0 ? 1.f : 0.f; so.y = s1 ? 1.f : 0.f;
            so.z = s2 ? 1.f : 0.f; so.w = s3 ? 1.f : 0.f;
            *reinterpret_cast<float4*>(out + i) = so;
            float4 po; po.x = p0; po.y = p1; po.z = p2; po.w = p3;
            *reinterpret_cast<float4*>(pbuf + i) = po;
        }

        // ---- Commit a (ascending step order; matches reference bit-exactly).
        if (s0) a4 = add4(a4, Wr0);
        if (s1) a4 = add4(a4, Wr1);
        if (s2) a4 = add4(a4, Wr2);
        if (s3) a4 = add4(a4, Wr3);

        Vr0 = Vn0; Vr1 = Vn1; Vr2 = Vn2; Vr3 = Vn3;
        Wr0 = Wn0; Wr1 = Wn1; Wr2 = Wn2; Wr3 = Wn3;
        bb = bbn; uu = uun;
    }
}

// ---------------------------------------------------------------------------
// logp = sum_{i<4094} s_i*log(p_i) + (1-s_i)*log1p(-p_i)
// ---------------------------------------------------------------------------
__global__ __launch_bounds__(256) void ar_logp(
    const float* __restrict__ pbuf, float* __restrict__ out)
{
    __shared__ float red[256];
    const int t = threadIdx.x;
    float acc = 0.f;
    for (int i = t; i < DIM_SOL - 2; i += 256) {
        const float p = pbuf[i];
        const float s = out[i];
        acc += (s > 0.5f) ? logf(p) : log1pf(-p);
    }
    red[t] = acc;
    __syncthreads();
    for (int w = 128; w >= 1; w >>= 1) {
        if (t < w) red[t] += red[t + w];
        __syncthreads();
    }
    if (t == 0) out[DIM_SOL] = red[0];
}

// ---------------------------------------------------------------------------
extern "C" void kernel_launch(void* const* d_in, const int* in_sizes, int n_in,
                              void* d_out, int out_size, void* d_ws, size_t ws_size,
                              hipStream_t stream)
{
    const float* context = (const float*)d_in[0];
    const float* u       = (const float*)d_in[1];
    const float* W       = (const float*)d_in[2];
    const float* V       = (const float*)d_in[3];
    const float* b       = (const float*)d_in[4];
    const float* c       = (const float*)d_in[5];
    float* out = (float*)d_out;

    char* ws = (char*)d_ws;
    unsigned long long* pub = (unsigned long long*)(ws);
    float* pbuf = (float*)(ws + 8192);
    float* a0   = (float*)(ws + 24576);
    float* Wp   = (float*)(ws + 65536);
    const size_t wp_bytes = (size_t)DIM_SOL * DIM_HID * sizeof(float);
    const int packed = (ws_size >= (size_t)65536 + wp_bytes) ? 1 : 0;

    hipLaunchKernelGGL(ar_prep, dim3(1024), dim3(256), 0, stream,
                       W, context, c, a0, Wp, packed);
    hipLaunchKernelGGL(ar_serial, dim3(NWG), dim3(64), 0, stream,
                       V, W, b, u, a0, Wp, pub, pbuf, out, packed);
    hipLaunchKernelGGL(ar_logp, dim3(1), dim3(256), 0, stream, pbuf, out);
}

// Round 4
// 2811.225 us; speedup vs baseline: 3.1193x; 1.8299x over previous
//
#include <hip/hip_runtime.h>
#include <cstdint>
#include <cstddef>

#define DIM_SOL 4096
#define DIM_CTX 4096
#define DIM_HID 8192
#define NWG 32                 // serial-phase workgroups (4 waves each)
#define NROUND (DIM_SOL / 4)   // K=4 steps per sync round

// Workspace layout (bytes):
//   [0,     8192)  : pub slots, 2 banks x 32 slots x 128B (16 u64; word w = {d_w bits | tag32})
//   [8192, 24576)  : pbuf, 4096 floats (per-step p, for logp reduction)
//   [24576,57344)  : a0, 8192 floats
//   [65536, +128MB): Wp packed transpose of W[:,4096:] (row i = column 4096+i of W)
// All pub traffic is RELAXED agent-scope atomics; each u64 carries its own tag
// (no fences -> no buffer_wbl2/buffer_inv, the round-2 killer). Harness poisons
// ws with 0xAA: tag dword 0xAAAAAAAA never equals a valid round tag (1..1024).

__device__ __forceinline__ float sigmoid_precise(float x) {
    return 1.0f / (1.0f + expf(-x));   // decode path: keep identical to passing config
}
__device__ __forceinline__ float hsig(float x) {
    // speculative h path: fast sigmoid (v_exp + v_rcp); ~1ulp -> logit err ~1e-7 rel
    return __builtin_amdgcn_rcpf(1.0f + __expf(-x));
}

// ---------------------------------------------------------------------------
// Prep: a0 GEMV (WGs 0..255) + transpose-pack of W's sol half (WGs 256..2047)
// ---------------------------------------------------------------------------
__global__ __launch_bounds__(256) void ar_prep(
    const float* __restrict__ W, const float* __restrict__ context,
    const float* __restrict__ c, float* __restrict__ a0,
    float* __restrict__ Wp, int packed)
{
    const int wg  = blockIdx.x;
    const int tid = threadIdx.x;

    if (wg < 256) {
        // a0[r] = c[r] + dot(W[r][0:4096], context); one wave per 8-row group.
        const int wave = wg * 4 + (tid >> 6);   // 0..1023
        const int lane = tid & 63;
        const float4* ctx4 = reinterpret_cast<const float4*>(context);
        const int r0 = wave * 8;
        for (int r = r0; r < r0 + 8; ++r) {
            const float4* Wr4 = reinterpret_cast<const float4*>(W + (size_t)r * DIM_HID);
            float acc = 0.f;
#pragma unroll
            for (int j = 0; j < 16; ++j) {
                float4 w4 = Wr4[lane + 64 * j];
                float4 x4 = ctx4[lane + 64 * j];
                acc = fmaf(w4.x, x4.x, acc);
                acc = fmaf(w4.y, x4.y, acc);
                acc = fmaf(w4.z, x4.z, acc);
                acc = fmaf(w4.w, x4.w, acc);
            }
#pragma unroll
            for (int off = 32; off >= 1; off >>= 1) acc += __shfl_xor(acc, off);
            if (lane == 0) a0[r] = c[r] + acc;
        }
    } else if (packed) {
        // Tiled 64x64 transpose: Wp[i][k] = W[k][4096+i]
        __shared__ float tile[64][65];
        const int tx = tid & 63, ty = tid >> 6;   // ty 0..3
        for (int t = wg - 256; t < 64 * 128; t += 1792) {
            const int i0 = (t & 63) * 64;   // sol tile
            const int k0 = (t >> 6) * 64;   // hidden tile
            __syncthreads();
#pragma unroll
            for (int dy = 0; dy < 64; dy += 4) {
                tile[dy + ty][tx] =
                    W[(size_t)(k0 + dy + ty) * DIM_HID + (DIM_CTX + i0 + tx)];
            }
            __syncthreads();
#pragma unroll
            for (int dy = 0; dy < 64; dy += 4) {
                Wp[(size_t)(i0 + dy + ty) * DIM_HID + (k0 + tx)] = tile[tx][dy + ty];
            }
        }
    }
}

// ---------------------------------------------------------------------------
// Serial phase: K=4 speculative steps per all-relaxed global sync round.
// 256 threads/WG (4 waves, 1 hidden elem per thread). 15 tree nodes in heap
// order: node(d,bits) = 2^d-1+bits.
// ---------------------------------------------------------------------------
__global__ __launch_bounds__(256) void ar_serial(
    const float* __restrict__ V, const float* __restrict__ W,
    const float* __restrict__ b, const float* __restrict__ u,
    const float* __restrict__ a0, const float* __restrict__ Wp,
    unsigned long long* __restrict__ pub,
    float* __restrict__ pbuf, float* __restrict__ out, int packed)
{
    const int g   = blockIdx.x;
    const int tid = threadIdx.x;
    const int wv  = tid >> 6;          // wave 0..3
    const int l   = tid & 63;          // lane
    const int w   = l & 15;            // value index owned after reduce-scatter
    const int sb  = l >> 4;            // base slot group for the poll (0..3)
    const int e   = g * 256 + tid;     // this thread's hidden element

    __shared__ float lred[2][64];      // ping-pong banks: [bank][w*4 + wave]

    const float4* b4 = reinterpret_cast<const float4*>(b);
    const float4* u4 = reinterpret_cast<const float4*>(u);

    float a = a0[e];

    auto loadW = [&](int i) -> float {
        if (packed) return Wp[(size_t)i * DIM_HID + e];
        return W[(size_t)e * DIM_HID + DIM_CTX + i];
    };

    float Vr0 = V[(size_t)0 * DIM_HID + e], Vr1 = V[(size_t)1 * DIM_HID + e];
    float Vr2 = V[(size_t)2 * DIM_HID + e], Vr3 = V[(size_t)3 * DIM_HID + e];
    float Wr0 = loadW(0), Wr1 = loadW(1), Wr2 = loadW(2), Wr3 = loadW(3);
    float4 bb = b4[0], uu = u4[0];

    for (int r = 0; r < NROUND; ++r) {
        const unsigned tag = (unsigned)(r + 1);
        unsigned long long* bank = pub + (size_t)(r & 1) * 512;   // 32 slots * 16 u64

        // ---- 8 h-variants (subsets of {Wr0,Wr1,Wr2}), ascending-add order.
        const float x1 = a + Wr0;
        const float x2 = a + Wr1;
        const float x3 = x1 + Wr1;
        const float x4 = a + Wr2;
        const float x5 = x1 + Wr2;
        const float x6 = x2 + Wr2;
        const float x7 = x3 + Wr2;
        const float h0 = hsig(a),  h1 = hsig(x1), h2 = hsig(x2), h3 = hsig(x3);
        const float h4 = hsig(x4), h5 = hsig(x5), h6 = hsig(x6), h7 = hsig(x7);

        // ---- 15 per-thread node products (heap order), padded to 16.
        float S[16];
        S[0] = Vr0 * h0;
        S[1] = Vr1 * h0;  S[2] = Vr1 * h1;
        S[3] = Vr2 * h0;  S[4] = Vr2 * h1;  S[5] = Vr2 * h2;  S[6] = Vr2 * h3;
        S[7] = Vr3 * h0;  S[8] = Vr3 * h1;  S[9] = Vr3 * h2;  S[10] = Vr3 * h3;
        S[11] = Vr3 * h4; S[12] = Vr3 * h5; S[13] = Vr3 * h6; S[14] = Vr3 * h7;
        S[15] = 0.0f;

        // ---- In-wave reduce-scatter over lane bits 0..3: value w -> lane w.
        {
            const bool hi1 = l & 1;
            float o[8];
#pragma unroll
            for (int j = 0; j < 8; ++j) {
                o[j] = hi1 ? S[2 * j] : S[2 * j + 1];
                S[j] = hi1 ? S[2 * j + 1] : S[2 * j];
            }
#pragma unroll
            for (int j = 0; j < 8; ++j) S[j] += __shfl_xor(o[j], 1);
        }
        {
            const bool hi2 = l & 2;
            float o[4];
#pragma unroll
            for (int j = 0; j < 4; ++j) {
                o[j] = hi2 ? S[2 * j] : S[2 * j + 1];
                S[j] = hi2 ? S[2 * j + 1] : S[2 * j];
            }
#pragma unroll
            for (int j = 0; j < 4; ++j) S[j] += __shfl_xor(o[j], 2);
        }
        {
            const bool hi3 = l & 4;
            float o[2];
#pragma unroll
            for (int j = 0; j < 2; ++j) {
                o[j] = hi3 ? S[2 * j] : S[2 * j + 1];
                S[j] = hi3 ? S[2 * j + 1] : S[2 * j];
            }
#pragma unroll
            for (int j = 0; j < 2; ++j) S[j] += __shfl_xor(o[j], 4);
        }
        {
            const bool hi4 = l & 8;
            float o0 = hi4 ? S[0] : S[1];
            float k0 = hi4 ? S[1] : S[0];
            S[0] = k0 + __shfl_xor(o0, 8);
        }
        float T = S[0];
        T += __shfl_xor(T, 16);
        T += __shfl_xor(T, 32);        // lane l holds wave-partial of value (l&15)

        // ---- Cross-wave combine via LDS (one barrier; ping-pong banks).
        if (l < 16) lred[r & 1][w * 4 + wv] = T;
        __syncthreads();
        if (wv == 0 && l < 15) {
            const float4 q = *reinterpret_cast<const float4*>(&lred[r & 1][w * 4]);
            const float Twg = ((q.x + q.y) + q.z) + q.w;
            unsigned long long v =
                ((unsigned long long)__float_as_uint(Twg) << 32) |
                (unsigned long long)tag;
            __hip_atomic_store(bank + (size_t)g * 16 + w, v,
                               __ATOMIC_RELAXED, __HIP_MEMORY_SCOPE_AGENT);
        }

        // ---- Prefetch next round's rows while the sync is in flight.
        float Vn0, Vn1, Vn2, Vn3, Wn0, Wn1, Wn2, Wn3;
        float4 bbn, uun;
        if (r + 1 < NROUND) {
            const int i1 = 4 * (r + 1);
            Vn0 = V[(size_t)(i1 + 0) * DIM_HID + e];
            Vn1 = V[(size_t)(i1 + 1) * DIM_HID + e];
            Vn2 = V[(size_t)(i1 + 2) * DIM_HID + e];
            Vn3 = V[(size_t)(i1 + 3) * DIM_HID + e];
            Wn0 = loadW(i1 + 0); Wn1 = loadW(i1 + 1);
            Wn2 = loadW(i1 + 2); Wn3 = loadW(i1 + 3);
            bbn = b4[r + 1]; uun = u4[r + 1];
        }

        // ---- Poll: lane reads word w of slots sb, sb+4, ..., sb+28.
        unsigned long long q0, q1, q2, q3, q4, q5, q6, q7;
        {
            unsigned long long* ms = bank + (size_t)sb * 16 + w;
            bool ok = (w == 15);
            for (;;) {
                if (!ok) {
                    q0 = __hip_atomic_load(ms + 0 * 64, __ATOMIC_RELAXED, __HIP_MEMORY_SCOPE_AGENT);
                    q1 = __hip_atomic_load(ms + 1 * 64, __ATOMIC_RELAXED, __HIP_MEMORY_SCOPE_AGENT);
                    q2 = __hip_atomic_load(ms + 2 * 64, __ATOMIC_RELAXED, __HIP_MEMORY_SCOPE_AGENT);
                    q3 = __hip_atomic_load(ms + 3 * 64, __ATOMIC_RELAXED, __HIP_MEMORY_SCOPE_AGENT);
                    q4 = __hip_atomic_load(ms + 4 * 64, __ATOMIC_RELAXED, __HIP_MEMORY_SCOPE_AGENT);
                    q5 = __hip_atomic_load(ms + 5 * 64, __ATOMIC_RELAXED, __HIP_MEMORY_SCOPE_AGENT);
                    q6 = __hip_atomic_load(ms + 6 * 64, __ATOMIC_RELAXED, __HIP_MEMORY_SCOPE_AGENT);
                    q7 = __hip_atomic_load(ms + 7 * 64, __ATOMIC_RELAXED, __HIP_MEMORY_SCOPE_AGENT);
                    ok = ((unsigned)q0 == tag) & ((unsigned)q1 == tag) &
                         ((unsigned)q2 == tag) & ((unsigned)q3 == tag) &
                         ((unsigned)q4 == tag) & ((unsigned)q5 == tag) &
                         ((unsigned)q6 == tag) & ((unsigned)q7 == tag);
                }
                if (__all(ok)) break;
            }
        }
        float G;
        {
            float p0 = __uint_as_float((unsigned)(q0 >> 32));
            float p1 = __uint_as_float((unsigned)(q1 >> 32));
            float p2 = __uint_as_float((unsigned)(q2 >> 32));
            float p3 = __uint_as_float((unsigned)(q3 >> 32));
            float p4 = __uint_as_float((unsigned)(q4 >> 32));
            float p5 = __uint_as_float((unsigned)(q5 >> 32));
            float p6 = __uint_as_float((unsigned)(q6 >> 32));
            float p7 = __uint_as_float((unsigned)(q7 >> 32));
            G = (w == 15) ? 0.0f
                          : ((((((p0 + p1) + p2) + p3) + p4) + p5) + p6) + p7;
        }
        G += __shfl_xor(G, 16);
        G += __shfl_xor(G, 32);        // lane l: total of node (l&15) over 32 slots

        const float T0 = __shfl(G, 0),  T1 = __shfl(G, 1),  T2 = __shfl(G, 2);
        const float T3 = __shfl(G, 3),  T4 = __shfl(G, 4),  T5 = __shfl(G, 5);
        const float T6 = __shfl(G, 6),  T7 = __shfl(G, 7),  T8 = __shfl(G, 8);
        const float T9 = __shfl(G, 9),  T10 = __shfl(G, 10), T11 = __shfl(G, 11);
        const float T12 = __shfl(G, 12), T13 = __shfl(G, 13), T14 = __shfl(G, 14);

        // ---- Decode 4 steps (identical uniform computation everywhere).
        const float p0 = sigmoid_precise(bb.x + T0);
        const bool  s0 = uu.x < p0;
        const float p1 = sigmoid_precise(bb.y + (s0 ? T2 : T1));
        const bool  s1 = uu.y < p1;
        const float t2a = s0 ? T4 : T3, t2b = s0 ? T6 : T5;
        const float p2 = sigmoid_precise(bb.z + (s1 ? t2b : t2a));
        const bool  s2 = uu.z < p2;
        const float t3a = s0 ? T8 : T7,   t3b = s0 ? T10 : T9;
        const float t3c = s0 ? T12 : T11, t3d = s0 ? T14 : T13;
        const float t3e = s1 ? t3b : t3a, t3f = s1 ? t3d : t3c;
        const float p3 = sigmoid_precise(bb.w + (s2 ? t3f : t3e));
        const bool  s3 = uu.w < p3;

        if (g == 0 && tid == 0) {
            const int i = 4 * r;
            float4 so; so.x = s0 ? 1.f : 0.f; so.y = s1 ? 1.f : 0.f;
            so.z = s2 ? 1.f : 0.f; so.w = s3 ? 1.f : 0.f;
            *reinterpret_cast<float4*>(out + i) = so;
            float4 po; po.x = p0; po.y = p1; po.z = p2; po.w = p3;
            *reinterpret_cast<float4*>(pbuf + i) = po;
        }

        // ---- Commit a (ascending step order; matches reference exactly).
        if (s0) a += Wr0;
        if (s1) a += Wr1;
        if (s2) a += Wr2;
        if (s3) a += Wr3;

        Vr0 = Vn0; Vr1 = Vn1; Vr2 = Vn2; Vr3 = Vn3;
        Wr0 = Wn0; Wr1 = Wn1; Wr2 = Wn2; Wr3 = Wn3;
        bb = bbn; uu = uun;
    }
}

// ---------------------------------------------------------------------------
// logp = sum_{i<4094} s_i*log(p_i) + (1-s_i)*log1p(-p_i)
// ---------------------------------------------------------------------------
__global__ __launch_bounds__(256) void ar_logp(
    const float* __restrict__ pbuf, float* __restrict__ out)
{
    __shared__ float red[256];
    const int t = threadIdx.x;
    float acc = 0.f;
    for (int i = t; i < DIM_SOL - 2; i += 256) {
        const float p = pbuf[i];
        const float s = out[i];
        acc += (s > 0.5f) ? logf(p) : log1pf(-p);
    }
    red[t] = acc;
    __syncthreads();
    for (int wdt = 128; wdt >= 1; wdt >>= 1) {
        if (t < wdt) red[t] += red[t + wdt];
        __syncthreads();
    }
    if (t == 0) out[DIM_SOL] = red[0];
}

// ---------------------------------------------------------------------------
extern "C" void kernel_launch(void* const* d_in, const int* in_sizes, int n_in,
                              void* d_out, int out_size, void* d_ws, size_t ws_size,
                              hipStream_t stream)
{
    const float* context = (const float*)d_in[0];
    const float* u       = (const float*)d_in[1];
    const float* W       = (const float*)d_in[2];
    const float* V       = (const float*)d_in[3];
    const float* b       = (const float*)d_in[4];
    const float* c       = (const float*)d_in[5];
    float* out = (float*)d_out;

    char* ws = (char*)d_ws;
    unsigned long long* pub = (unsigned long long*)(ws);
    float* pbuf = (float*)(ws + 8192);
    float* a0   = (float*)(ws + 24576);
    float* Wp   = (float*)(ws + 65536);
    const size_t wp_bytes = (size_t)DIM_SOL * DIM_HID * sizeof(float);
    const int packed = (ws_size >= (size_t)65536 + wp_bytes) ? 1 : 0;

    hipLaunchKernelGGL(ar_prep, dim3(2048), dim3(256), 0, stream,
                       W, context, c, a0, Wp, packed);
    hipLaunchKernelGGL(ar_serial, dim3(NWG), dim3(256), 0, stream,
                       V, W, b, u, a0, Wp, pub, pbuf, out, packed);
    hipLaunchKernelGGL(ar_logp, dim3(1), dim3(256), 0, stream, pbuf, out);
}